// Round 1
// baseline (341.354 us; speedup 1.0000x reference)
//
#include <hip/hip_runtime.h>
#include <math.h>

#define E   2048
#define H   16
#define DH  128
#define L   8192
#define L1  8193
#define SS  8256            // score row stride (padded)

// ws float offsets
#define WS_Q    0
#define WS_KI   2048
#define WS_VI   4096
#define WS_ACC  6144
#define WS_SC   8192
#define WS_M    (WS_SC + H * SS)     // 140288
#define WS_SUM  (WS_M + 16)

__global__ __launch_bounds__(256) void init_kernel(const float* __restrict__ bq,
                                                   const float* __restrict__ bk,
                                                   const float* __restrict__ bv,
                                                   const float* __restrict__ bo,
                                                   float* __restrict__ ws,
                                                   float* __restrict__ out) {
    int j = blockIdx.x * 256 + threadIdx.x;
    if (j < E) {
        ws[WS_Q  + j] = bq[j];
        ws[WS_KI + j] = bk[j];
        ws[WS_VI + j] = bv[j];
        ws[WS_ACC + j] = 0.f;
        out[j] = bo[j];
    }
}

// q/k_i/v_i projections: x[2048] @ W[2048x2048] + b (bias pre-seeded by init).
// Split-K: blocks = 3 matrices x 8 j-blocks(256 outs) x 16 k-chunks(128).
__global__ __launch_bounds__(256) void proj_kernel(const float* __restrict__ x,
                                                   const float* __restrict__ Wq,
                                                   const float* __restrict__ Wk,
                                                   const float* __restrict__ Wv,
                                                   float* __restrict__ ws) {
    const int JB = E / 256;          // 8
    const int KC = E / 128;          // 16
    int b = blockIdx.x;
    int m = b / (JB * KC);
    int r = b % (JB * KC);
    int jb = r / KC, kc = r % KC;
    const float* W = (m == 0) ? Wq : (m == 1) ? Wk : Wv;
    float* dst = ws + ((m == 0) ? WS_Q : (m == 1) ? WS_KI : WS_VI);

    __shared__ float xs[128];
    int t = threadIdx.x;
    if (t < 128) xs[t] = x[kc * 128 + t];
    __syncthreads();

    int j = jb * 256 + t;
    const float* Wp = W + (size_t)(kc * 128) * E + j;
    float acc = 0.f;
#pragma unroll 8
    for (int i = 0; i < 128; ++i) acc += xs[i] * Wp[(size_t)i * E];
    atomicAdd(dst + j, acc);
}

// Fused: copy k-cache (+ appended k_i row) to out_k AND compute scores.
// One 64-lane wave per (l,h) row: each lane loads float2 (512B/row coalesced).
__global__ __launch_bounds__(256) void score_kernel(const float* __restrict__ kcache,
                                                    float* __restrict__ ws,
                                                    float* __restrict__ out_k) {
    int wave = threadIdx.x >> 6;
    int lane = threadIdx.x & 63;
    int p = blockIdx.x * 4 + wave;
    if (p >= H * L1) return;
    int l = p >> 4;
    int h = p & 15;

    float2 kv;
    if (l < L) kv = *(const float2*)(kcache + ((size_t)l * H + h) * DH + lane * 2);
    else       kv = *(const float2*)(ws + WS_KI + h * DH + lane * 2);
    *(float2*)(out_k + ((size_t)l * H + h) * DH + lane * 2) = kv;

    float2 qv = *(const float2*)(ws + WS_Q + h * DH + lane * 2);
    float d = qv.x * kv.x + qv.y * kv.y;
#pragma unroll
    for (int off = 32; off > 0; off >>= 1) d += __shfl_down(d, off);
    if (lane == 0) ws[WS_SC + h * SS + l] = d * 0.08838834764831845f;  // 1/sqrt(128)
}

// Per-head softmax statistics: m[h], 1/sum[h].
__global__ __launch_bounds__(256) void smax_kernel(float* __restrict__ ws) {
    int h = blockIdx.x;
    int t = threadIdx.x;
    __shared__ float red[256];
    const float* s = ws + WS_SC + h * SS;

    float m = -INFINITY;
    for (int l = t; l < L1; l += 256) m = fmaxf(m, s[l]);
    red[t] = m; __syncthreads();
    for (int o = 128; o > 0; o >>= 1) {
        if (t < o) red[t] = fmaxf(red[t], red[t + o]);
        __syncthreads();
    }
    m = red[0]; __syncthreads();

    float sum = 0.f;
    for (int l = t; l < L1; l += 256) sum += __expf(s[l] - m);
    red[t] = sum; __syncthreads();
    for (int o = 128; o > 0; o >>= 1) {
        if (t < o) red[t] += red[t + o];
        __syncthreads();
    }
    if (t == 0) { ws[WS_M + h] = m; ws[WS_SUM + h] = 1.f / red[0]; }
}

// Fused: copy v-cache (+ appended v_i row) to out_v AND accumulate attn @ V.
// Block = (head h, chunk of 128 keys); 256 threads = 2 key-streams x 128 dims.
__global__ __launch_bounds__(256) void pv_kernel(const float* __restrict__ vcache,
                                                 float* __restrict__ ws,
                                                 float* __restrict__ out_v) {
    int h = blockIdx.y;
    int c = blockIdx.x;
    int t = threadIdx.x;
    int d = t & 127;
    int half = t >> 7;
    int l0 = c * 128;
    int lend = min(l0 + 128, L1);
    float m   = ws[WS_M + h];
    float inv = ws[WS_SUM + h];

    float acc = 0.f;
    for (int l = l0 + half; l < lend; l += 2) {
        float w = __expf(ws[WS_SC + h * SS + l] - m) * inv;
        float vv;
        if (l < L) vv = vcache[((size_t)l * H + h) * DH + d];
        else       vv = ws[WS_VI + h * DH + d];
        out_v[((size_t)l * H + h) * DH + d] = vv;
        acc += w * vv;
    }
    __shared__ float red[256];
    red[t] = acc; __syncthreads();
    if (t < 128) atomicAdd(ws + WS_ACC + h * DH + d, red[t] + red[t + 128]);
}

// out_i = values @ Wo + bo (bias pre-seeded by init). Split-K like proj.
__global__ __launch_bounds__(256) void outproj_kernel(const float* __restrict__ Wo,
                                                      const float* __restrict__ ws,
                                                      float* __restrict__ out) {
    const int KC = E / 128;          // 16
    int jb = blockIdx.x / KC, kc = blockIdx.x % KC;
    __shared__ float xs[128];
    int t = threadIdx.x;
    if (t < 128) xs[t] = ws[WS_ACC + kc * 128 + t];
    __syncthreads();

    int j = jb * 256 + t;
    const float* Wp = Wo + (size_t)(kc * 128) * E + j;
    float a = 0.f;
#pragma unroll 8
    for (int i = 0; i < 128; ++i) a += xs[i] * Wp[(size_t)i * E];
    atomicAdd(out + j, a);
}

extern "C" void kernel_launch(void* const* d_in, const int* in_sizes, int n_in,
                              void* d_out, int out_size, void* d_ws, size_t ws_size,
                              hipStream_t stream) {
    const float* x  = (const float*)d_in[0];
    const float* v  = (const float*)d_in[1];
    const float* k  = (const float*)d_in[2];
    const float* Wv = (const float*)d_in[3];
    const float* bv = (const float*)d_in[4];
    const float* Wq = (const float*)d_in[5];
    const float* bq = (const float*)d_in[6];
    const float* Wk = (const float*)d_in[7];
    const float* bk = (const float*)d_in[8];
    const float* Wo = (const float*)d_in[9];
    const float* bo = (const float*)d_in[10];
    float* out = (float*)d_out;
    float* ws  = (float*)d_ws;
    float* out_v = out + E;
    float* out_k = out + E + (size_t)L1 * E;

    init_kernel<<<8, 256, 0, stream>>>(bq, bk, bv, bo, ws, out);
    proj_kernel<<<3 * 8 * 16, 256, 0, stream>>>(x, Wq, Wk, Wv, ws);
    score_kernel<<<(H * L1 + 3) / 4, 256, 0, stream>>>(k, ws, out_k);
    smax_kernel<<<16, 256, 0, stream>>>(ws);
    pv_kernel<<<dim3((L1 + 127) / 128, H), 256, 0, stream>>>(v, ws, out_v);
    outproj_kernel<<<8 * 16, 256, 0, stream>>>(Wo, ws, out);
}